// Round 3
// baseline (619.465 us; speedup 1.0000x reference)
//
#include <hip/hip_runtime.h>
#include <math.h>

#define BB 2
#define LL 2048
#define DMODEL 1024
#define NHEAD 16
#define MTOK 4096            // BB*LL
#define KVB 64               // attention KV tile rows
#define NT (LL / KVB)        // 32 KV tiles

typedef unsigned short u16;
typedef __attribute__((ext_vector_type(8))) short short8;
typedef __attribute__((ext_vector_type(4))) float f32x4;

// ---------------------------------------------------------------------------
// bf16 split helpers: x ≈ bf2f(hi) + bf2f(lo), residual ~2^-17 x
// ---------------------------------------------------------------------------
__device__ __host__ inline u16 f2bf(float f) {
    unsigned u = __builtin_bit_cast(unsigned, f);
    return (u16)((u + 0x7FFFu + ((u >> 16) & 1u)) >> 16);   // RNE
}
__device__ inline float bf2f(u16 h) {
    unsigned u = ((unsigned)h) << 16;
    return __builtin_bit_cast(float, u);
}

// ---------------------------------------------------------------------------
// fp32 -> (hi, lo) bf16 plane converter, float4-vectorized, grid-stride.
// ---------------------------------------------------------------------------
__global__ __launch_bounds__(256)
void split_planes(const float* __restrict__ x, u16* __restrict__ hi,
                  u16* __restrict__ lo, int n4)
{
    for (int i = blockIdx.x * blockDim.x + threadIdx.x; i < n4;
         i += gridDim.x * blockDim.x) {
        float4 v = ((const float4*)x)[i];
        ushort4 h, l;
        h.x = f2bf(v.x); l.x = f2bf(v.x - bf2f(h.x));
        h.y = f2bf(v.y); l.y = f2bf(v.y - bf2f(h.y));
        h.z = f2bf(v.z); l.z = f2bf(v.z - bf2f(h.z));
        h.w = f2bf(v.w); l.w = f2bf(v.w - bf2f(h.w));
        ((ushort4*)hi)[i] = h;
        ((ushort4*)lo)[i] = l;
    }
}

// ---------------------------------------------------------------------------
// Split-bf16 MFMA GEMM (torch Linear NT): Y[m,n] = (sum_k X[m,k]W[n,k]+b[n])*scale
// via Xhi*Whi + Xhi*Wlo + Xlo*Whi. BM=128, BN=64, BK=32, 4 waves, wave tile
// 64x32 (4x2 frags of 16x16x32). global_load_lds w=16, linear LDS, source-side
// swizzle kl = ci ^ ((r>>1)&3); frag reads undo it -> ~2-way conflicts.
// mode 0: fp32 Y. mode 1: (hi,lo) planes [m][N]. mode 2: transposed planes [n][MTOK].
// ---------------------------------------------------------------------------
#define GBM 128
#define GBN 64
#define GBK 32

__global__ __launch_bounds__(256)
void gemm_mfma_split(const u16* __restrict__ Ahi, const u16* __restrict__ Alo,
                     const u16* __restrict__ Bhi, const u16* __restrict__ Blo,
                     const float* __restrict__ bias, float scale, int K, int N,
                     float* __restrict__ Yf, u16* __restrict__ Yhi,
                     u16* __restrict__ Ylo, int mode)
{
    // per buffer (u16): Ahi[0,4096) Alo[4096,8192) Bhi[8192,10240) Blo[10240,12288)
    __shared__ u16 lds[2][12288];

    const int tid = threadIdx.x;
    const int lid = tid & 63;
    const int w   = tid >> 6;
    const int wm  = w >> 1, wn = w & 1;
    const int m0  = blockIdx.y * GBM;
    const int n0  = blockIdx.x * GBN;

    f32x4 acc[4][2];
    #pragma unroll
    for (int ms = 0; ms < 4; ++ms)
        #pragma unroll
        for (int ns = 0; ns < 2; ++ns)
            acc[ms][ns] = (f32x4){0.f, 0.f, 0.f, 0.f};

    auto stage = [&](int buf, int t) {
        const int k0 = t * GBK;
        #pragma unroll
        for (int j = 0; j < 6; ++j) {
            const int q = w * 6 + j;
            const u16* plane; int ldsoff, c, R0;
            if (q < 8)       { plane = Ahi; ldsoff = 0;     c = q;      R0 = m0; }
            else if (q < 16) { plane = Alo; ldsoff = 4096;  c = q - 8;  R0 = m0; }
            else if (q < 20) { plane = Bhi; ldsoff = 8192;  c = q - 16; R0 = n0; }
            else             { plane = Blo; ldsoff = 10240; c = q - 20; R0 = n0; }
            const int r  = c * 16 + (lid >> 2);
            const int ci = lid & 3;
            const int kl = ci ^ ((r >> 1) & 3);
            const u16* g = plane + (size_t)(R0 + r) * K + k0 + kl * 8;
            __builtin_amdgcn_global_load_lds(
                (const __attribute__((address_space(1))) void*)g,
                (__attribute__((address_space(3))) void*)(&lds[buf][ldsoff + c * 512]),
                16, 0, 0);
        }
    };

    auto compute = [&](int buf) {
        const u16* L = lds[buf];
        short8 ah[4], al[4], bh[2], bl[2];
        #pragma unroll
        for (int ms = 0; ms < 4; ++ms) {
            const int r   = wm * 64 + ms * 16 + (lid & 15);
            const int off = r * 32 + (((lid >> 4) ^ ((r >> 1) & 3)) * 8);
            ah[ms] = *(const short8*)&L[off];
            al[ms] = *(const short8*)&L[4096 + off];
        }
        #pragma unroll
        for (int ns = 0; ns < 2; ++ns) {
            const int r   = wn * 32 + ns * 16 + (lid & 15);
            const int off = r * 32 + (((lid >> 4) ^ ((r >> 1) & 3)) * 8);
            bh[ns] = *(const short8*)&L[8192 + off];
            bl[ns] = *(const short8*)&L[10240 + off];
        }
        #pragma unroll
        for (int ms = 0; ms < 4; ++ms)
            #pragma unroll
            for (int ns = 0; ns < 2; ++ns) {
                acc[ms][ns] = __builtin_amdgcn_mfma_f32_16x16x32_bf16(al[ms], bh[ns], acc[ms][ns], 0, 0, 0);
                acc[ms][ns] = __builtin_amdgcn_mfma_f32_16x16x32_bf16(ah[ms], bl[ns], acc[ms][ns], 0, 0, 0);
                acc[ms][ns] = __builtin_amdgcn_mfma_f32_16x16x32_bf16(ah[ms], bh[ns], acc[ms][ns], 0, 0, 0);
            }
    };

    const int nt = K / GBK;
    stage(0, 0);
    __syncthreads();
    for (int t = 0; t < nt; ++t) {
        const int buf = t & 1;
        if (t + 1 < nt) stage(buf ^ 1, t + 1);
        compute(buf);
        __syncthreads();
    }

    // epilogue: D layout col = lid&15, row = (lid>>4)*4 + i
    const int orow = (lid >> 4) * 4;
    #pragma unroll
    for (int ms = 0; ms < 4; ++ms)
        #pragma unroll
        for (int ns = 0; ns < 2; ++ns) {
            const int col = n0 + wn * 32 + ns * 16 + (lid & 15);
            const float bcol = bias[col];
            #pragma unroll
            for (int i = 0; i < 4; ++i) {
                const int row = m0 + wm * 64 + ms * 16 + orow + i;
                const float y = (acc[ms][ns][i] + bcol) * scale;
                if (mode == 0) {
                    Yf[(size_t)row * N + col] = y;
                } else if (mode == 1) {
                    const size_t idx = (size_t)row * N + col;
                    const u16 hh = f2bf(y);
                    Yhi[idx] = hh;
                    Ylo[idx] = f2bf(y - bf2f(hh));
                } else {  // mode 2: transposed planes [n][MTOK]
                    const size_t idx = (size_t)col * MTOK + row;
                    const u16 hh = f2bf(y);
                    Yhi[idx] = hh;
                    Ylo[idx] = f2bf(y - bf2f(hh));
                }
            }
        }
}

// ---------------------------------------------------------------------------
// Split-bf16 MFMA flash attention. Block = (b, h, 128 q-rows), 4 waves,
// wave = 32 q-rows. KV tiles of 64 rows, double-buffered in LDS.
// LDS: pp (32 KB, Q staging scratch then wave-private fp32 P) + kvb (64 KB).
// All tiles: row*64 u16, slot' = slot ^ (r&7) (16B slots); P fp32: row*64 f32,
// slot' = slot ^ ((r&7)<<1) (16B slots of 4 f32).
// ---------------------------------------------------------------------------
__global__ __launch_bounds__(256, 1)
void attn_mfma(const u16* __restrict__ qph, const u16* __restrict__ qpl,
               const u16* __restrict__ kph, const u16* __restrict__ kpl,
               const u16* __restrict__ vth, const u16* __restrict__ vtl,
               const float* __restrict__ qmask, const float* __restrict__ kmask,
               const float* __restrict__ pos,
               u16* __restrict__ ach, u16* __restrict__ acl)
{
    __shared__ float pp[4][2048];       // 32 KB: Q scratch, then per-wave P
    __shared__ u16  kvb[2][4][4096];    // 64 KB: [buf][Kh,Kl,Vth,Vtl][64x64]

    const int tid  = threadIdx.x;
    const int lid  = tid & 63;
    const int w    = tid >> 6;
    const int lo16 = lid & 15;
    const int hi4  = lid >> 4;
    const int qt = blockIdx.x, h = blockIdx.y, b = blockIdx.z;
    const int q0 = qt * 128;

    // ---- stage Q (hi/lo planes) into pp scratch: 32 chunks of 512 u16 ----
    {
        u16* qs = (u16*)pp;
        #pragma unroll
        for (int j = 0; j < 8; ++j) {
            const int cid = w * 8 + j;           // 0..31
            const int p   = cid >> 4;            // 0=hi, 1=lo
            const int rg  = cid & 15;
            const int r   = rg * 8 + (lid >> 3); // q-local row 0..127
            const int sp  = (lid & 7) ^ (r & 7); // source slot (inverse swizzle)
            const u16* src = (p ? qpl : qph) +
                (size_t)(b * LL + q0 + r) * DMODEL + h * 64 + sp * 8;
            __builtin_amdgcn_global_load_lds(
                (const __attribute__((address_space(1))) void*)src,
                (__attribute__((address_space(3))) void*)(qs + cid * 512), 16, 0, 0);
        }
    }

    // ---- KV tile staging: 32 chunks (4 planes x 8 row-groups) ----
    auto stage = [&](int buf, int t) {
        const int k0 = t * KVB;
        #pragma unroll
        for (int j = 0; j < 8; ++j) {
            const int cid = w * 8 + j;           // 0..31
            const int p   = cid >> 3;            // plane 0..3
            const int rg  = cid & 7;
            const int r   = rg * 8 + (lid >> 3); // tile row 0..63
            const int sp  = (lid & 7) ^ (r & 7);
            const u16* src;
            if (p == 0)      src = kph + (size_t)(b * LL + k0 + r) * DMODEL + h * 64 + sp * 8;
            else if (p == 1) src = kpl + (size_t)(b * LL + k0 + r) * DMODEL + h * 64 + sp * 8;
            else if (p == 2) src = vth + (size_t)(h * 64 + r) * MTOK + b * LL + k0 + sp * 8;
            else             src = vtl + (size_t)(h * 64 + r) * MTOK + b * LL + k0 + sp * 8;
            __builtin_amdgcn_global_load_lds(
                (const __attribute__((address_space(1))) void*)src,
                (__attribute__((address_space(3))) void*)(&kvb[buf][p][rg * 512]), 16, 0, 0);
        }
    };

    stage(0, 0);
    __syncthreads();   // Q + KV tile 0 landed

    // ---- read Q A-frags (hoisted for whole kernel), then free pp for P ----
    short8 qh[2][2], ql[2][2];
    {
        const u16* qs = (const u16*)pp;
        #pragma unroll
        for (int mf = 0; mf < 2; ++mf)
            #pragma unroll
            for (int ks = 0; ks < 2; ++ks) {
                const int r   = w * 32 + mf * 16 + lo16;
                const int off = r * 64 + (((ks * 4 + hi4) ^ (r & 7)) * 8);
                qh[mf][ks] = *(const short8*)(qs + off);
                ql[mf][ks] = *(const short8*)(qs + 8192 + off);
            }
    }
    __syncthreads();   // everyone done reading Q; pp now P region

    float m_run[2][4], l_run[2][4], qml[2][4];
    f32x4 o_acc[2][4];
    #pragma unroll
    for (int mf = 0; mf < 2; ++mf)
        #pragma unroll
        for (int i = 0; i < 4; ++i) {
            m_run[mf][i] = -INFINITY;
            l_run[mf][i] = 0.f;
            qml[mf][i]   = qmask[b * LL + q0 + w * 32 + mf * 16 + hi4 * 4 + i];
        }
    #pragma unroll
    for (int mf = 0; mf < 2; ++mf)
        #pragma unroll
        for (int nfd = 0; nfd < 4; ++nfd)
            o_acc[mf][nfd] = (f32x4){0.f, 0.f, 0.f, 0.f};

    for (int t = 0; t < NT; ++t) {
        const int buf = t & 1;
        const int k0  = t * KVB;

        // ---- pos + kmask loads first (stay in flight under QK^T) ----
        float posr[2][4][4], kmv[4];
        #pragma unroll
        for (int nf = 0; nf < 4; ++nf)
            kmv[nf] = kmask[b * LL + k0 + nf * 16 + lo16];
        #pragma unroll
        for (int mf = 0; mf < 2; ++mf)
            #pragma unroll
            for (int i = 0; i < 4; ++i) {
                const float* pr = pos +
                    ((size_t)(b * LL + q0 + w * 32 + mf * 16 + hi4 * 4 + i)) * LL +
                    k0 + lo16;
                #pragma unroll
                for (int nf = 0; nf < 4; ++nf)
                    posr[mf][i][nf] = pr[nf * 16];
            }

        // ---- prefetch next KV tile ----
        if (t + 1 < NT) stage(buf ^ 1, t + 1);

        // ---- S = Q K^T (3-term split) ----
        f32x4 s_acc[2][4];
        #pragma unroll
        for (int mf = 0; mf < 2; ++mf)
            #pragma unroll
            for (int nf = 0; nf < 4; ++nf)
                s_acc[mf][nf] = (f32x4){0.f, 0.f, 0.f, 0.f};

        #pragma unroll
        for (int ks = 0; ks < 2; ++ks)
            #pragma unroll
            for (int nf = 0; nf < 4; ++nf) {
                const int r   = nf * 16 + lo16;
                const int off = r * 64 + (((ks * 4 + hi4) ^ (r & 7)) * 8);
                short8 bh = *(const short8*)(&kvb[buf][0][0] + off);
                short8 bl = *(const short8*)(&kvb[buf][1][0] + off);
                #pragma unroll
                for (int mf = 0; mf < 2; ++mf) {
                    s_acc[mf][nf] = __builtin_amdgcn_mfma_f32_16x16x32_bf16(ql[mf][ks], bh, s_acc[mf][nf], 0, 0, 0);
                    s_acc[mf][nf] = __builtin_amdgcn_mfma_f32_16x16x32_bf16(qh[mf][ks], bl, s_acc[mf][nf], 0, 0, 0);
                    s_acc[mf][nf] = __builtin_amdgcn_mfma_f32_16x16x32_bf16(qh[mf][ks], bh, s_acc[mf][nf], 0, 0, 0);
                }
            }

        // ---- mask + pos + online softmax; write P (fp32) to wave-private LDS ----
        #pragma unroll
        for (int mf = 0; mf < 2; ++mf)
            #pragma unroll
            for (int i = 0; i < 4; ++i) {
                const int r = mf * 16 + hi4 * 4 + i;    // local q row
                float v[4];
                #pragma unroll
                for (int nf = 0; nf < 4; ++nf)
                    v[nf] = (qml[mf][i] * kmv[nf] == 0.f)
                            ? -INFINITY : s_acc[mf][nf][i] + posr[mf][i][nf];
                float rm = fmaxf(fmaxf(v[0], v[1]), fmaxf(v[2], v[3]));
                rm = fmaxf(rm, __shfl_xor(rm, 1));
                rm = fmaxf(rm, __shfl_xor(rm, 2));
                rm = fmaxf(rm, __shfl_xor(rm, 4));
                rm = fmaxf(rm, __shfl_xor(rm, 8));
                const float mn = fmaxf(m_run[mf][i], rm);
                const float c  = __expf(m_run[mf][i] - mn);
                float ls = 0.f;
                #pragma unroll
                for (int nf = 0; nf < 4; ++nf) {
                    const float pv = __expf(v[nf] - mn);
                    const int col  = nf * 16 + lo16;
                    const int sl   = (col >> 2) ^ ((r & 7) << 1);
                    pp[w][r * 64 + sl * 4 + (col & 3)] = pv;
                    ls += pv;
                }
                ls += __shfl_xor(ls, 1);
                ls += __shfl_xor(ls, 2);
                ls += __shfl_xor(ls, 4);
                ls += __shfl_xor(ls, 8);
                l_run[mf][i] = l_run[mf][i] * c + ls;
                m_run[mf][i] = mn;
                #pragma unroll
                for (int nfd = 0; nfd < 4; ++nfd)
                    o_acc[mf][nfd][i] *= c;
            }

        // ---- PV: read P A-frags (trunc-split to bf16), V^T B-frags, MFMA ----
        #pragma unroll
        for (int ks = 0; ks < 2; ++ks) {
            short8 pah[2], pal[2];
            #pragma unroll
            for (int mf = 0; mf < 2; ++mf) {
                const int r  = mf * 16 + lo16;
                const int sA = (ks * 8 + hi4 * 2)     ^ ((r & 7) << 1);
                const int sB = (ks * 8 + hi4 * 2 + 1) ^ ((r & 7) << 1);
                f32x4 pa = *(const f32x4*)&pp[w][r * 64 + sA * 4];
                f32x4 pb = *(const f32x4*)&pp[w][r * 64 + sB * 4];
                float f[8] = {pa[0], pa[1], pa[2], pa[3], pb[0], pb[1], pb[2], pb[3]};
                short8 hv, lv;
                #pragma unroll
                for (int jj = 0; jj < 8; ++jj) {
                    const unsigned u = __builtin_bit_cast(unsigned, f[jj]);
                    hv[jj] = (short)(u >> 16);                       // trunc hi
                    const float lof = f[jj] - __builtin_bit_cast(float, u & 0xFFFF0000u);
                    lv[jj] = (short)(__builtin_bit_cast(unsigned, lof) >> 16);
                }
                pah[mf] = hv; pal[mf] = lv;
            }
            #pragma unroll
            for (int nfd = 0; nfd < 4; ++nfd) {
                const int r   = nfd * 16 + lo16;
                const int off = r * 64 + (((ks * 4 + hi4) ^ (r & 7)) * 8);
                short8 bh = *(const short8*)(&kvb[buf][2][0] + off);
                short8 bl = *(const short8*)(&kvb[buf][3][0] + off);
                #pragma unroll
                for (int mf = 0; mf < 2; ++mf) {
                    o_acc[mf][nfd] = __builtin_amdgcn_mfma_f32_16x16x32_bf16(pal[mf], bh, o_acc[mf][nfd], 0, 0, 0);
                    o_acc[mf][nfd] = __builtin_amdgcn_mfma_f32_16x16x32_bf16(pah[mf], bl, o_acc[mf][nfd], 0, 0, 0);
                    o_acc[mf][nfd] = __builtin_amdgcn_mfma_f32_16x16x32_bf16(pah[mf], bh, o_acc[mf][nfd], 0, 0, 0);
                }
            }
        }

        __syncthreads();   // drain prefetch, protect kvb swap
    }

    // ---- normalize + write combined-head (hi,lo) planes [B*L][DMODEL] ----
    #pragma unroll
    for (int mf = 0; mf < 2; ++mf)
        #pragma unroll
        for (int i = 0; i < 4; ++i) {
            const float inv = 1.0f / l_run[mf][i];
            const size_t row = (size_t)(b * LL + q0 + w * 32 + mf * 16 + hi4 * 4 + i);
            #pragma unroll
            for (int nfd = 0; nfd < 4; ++nfd) {
                const float y = o_acc[mf][nfd][i] * inv;
                const u16 hh  = f2bf(y);
                const size_t idx = row * DMODEL + h * 64 + nfd * 16 + lo16;
                ach[idx] = hh;
                acl[idx] = f2bf(y - bf2f(hh));
            }
        }
}

// ---------------------------------------------------------------------------
extern "C" void kernel_launch(void* const* d_in, const int* in_sizes, int n_in,
                              void* d_out, int out_size, void* d_ws, size_t ws_size,
                              hipStream_t stream)
{
    const float* q     = (const float*)d_in[0];
    const float* k     = (const float*)d_in[1];
    const float* qmask = (const float*)d_in[2];
    const float* kmask = (const float*)d_in[3];
    const float* pos   = (const float*)d_in[4];
    const float* Wq    = (const float*)d_in[5];
    const float* bq    = (const float*)d_in[6];
    const float* Wk    = (const float*)d_in[7];
    const float* bk    = (const float*)d_in[8];
    const float* Wv    = (const float*)d_in[9];
    const float* bv    = (const float*)d_in[10];
    const float* Wo    = (const float*)d_in[11];
    const float* bo    = (const float*)d_in[12];
    float* out = (float*)d_out;

    const size_t P  = (size_t)MTOK * DMODEL;   // 4M elems / plane
    const size_t PW = (size_t)DMODEL * DMODEL;

    u16* base = (u16*)d_ws;
    u16* qp_h = base;            u16* qp_l = qp_h + P;
    u16* kp_h = base + 2 * P;    u16* kp_l = kp_h + P;
    u16* bufA = base + 4 * P;    // q-input planes, later V^T planes (2P)
    u16* bufB = base + 6 * P;    // k-input planes, later attn-out planes (2P)
    u16* wq_h = base + 8 * P;    u16* wq_l = wq_h + PW;
    u16* wk_h = wq_l + PW;       u16* wk_l = wk_h + PW;
    u16* wv_h = wk_l + PW;       u16* wv_l = wv_h + PW;
    u16* wo_h = wv_l + PW;       u16* wo_l = wo_h + PW;
    // total: 8P + 8PW u16 = 80 MB

    split_planes<<<1024, 256, 0, stream>>>(q,  bufA, bufA + P, (int)(P / 4));
    split_planes<<<1024, 256, 0, stream>>>(k,  bufB, bufB + P, (int)(P / 4));
    split_planes<<<512,  256, 0, stream>>>(Wq, wq_h, wq_l, (int)(PW / 4));
    split_planes<<<512,  256, 0, stream>>>(Wk, wk_h, wk_l, (int)(PW / 4));
    split_planes<<<512,  256, 0, stream>>>(Wv, wv_h, wv_l, (int)(PW / 4));
    split_planes<<<512,  256, 0, stream>>>(Wo, wo_h, wo_l, (int)(PW / 4));

    const dim3 gb(DMODEL / GBN, MTOK / GBM);   // (16, 32) = 512 blocks
    const dim3 ga(LL / 128, NHEAD, BB);        // (16, 16, 2) = 512 blocks

    // qp = (q @ Wq^T + bq) * dkh^-0.5   -> planes [m][N]
    gemm_mfma_split<<<gb, 256, 0, stream>>>(bufA, bufA + P, wq_h, wq_l, bq, 0.125f,
                                            DMODEL, DMODEL, nullptr, qp_h, qp_l, 1);
    // kp = k @ Wk^T + bk                -> planes [m][N]
    gemm_mfma_split<<<gb, 256, 0, stream>>>(bufB, bufB + P, wk_h, wk_l, bk, 1.0f,
                                            DMODEL, DMODEL, nullptr, kp_h, kp_l, 1);
    // vpT = (kp @ Wv^T + bv)^T          -> transposed planes [n][MTOK] (into bufA)
    gemm_mfma_split<<<gb, 256, 0, stream>>>(kp_h, kp_l, wv_h, wv_l, bv, 1.0f,
                                            DMODEL, DMODEL, nullptr, bufA, bufA + P, 2);
    // flash attention (split-bf16 MFMA) -> combined-head planes (into bufB)
    attn_mfma<<<ga, 256, 0, stream>>>(qp_h, qp_l, kp_h, kp_l, bufA, bufA + P,
                                      qmask, kmask, pos, bufB, bufB + P);
    // out = ac @ Wo^T + bo              -> fp32 d_out
    gemm_mfma_split<<<gb, 256, 0, stream>>>(bufB, bufB + P, wo_h, wo_l, bo, 1.0f,
                                            DMODEL, DMODEL, out, nullptr, nullptr, 0);
}

// Round 4
// 477.682 us; speedup vs baseline: 1.2968x; 1.2968x over previous
//
#include <hip/hip_runtime.h>
#include <math.h>

#define BB 2
#define LL 2048
#define DMODEL 1024
#define NHEAD 16
#define MTOK 4096            // BB*LL
#define KVB 32               // attention KV tile rows
#define NT (LL / KVB)        // 64 KV tiles

typedef unsigned short u16;
typedef __attribute__((ext_vector_type(8))) short short8;
typedef __attribute__((ext_vector_type(4))) float f32x4;

// ---------------------------------------------------------------------------
// bf16 split helpers: x ≈ bf2f(hi) + bf2f(lo), residual ~2^-17 x
// ---------------------------------------------------------------------------
__device__ __host__ inline u16 f2bf(float f) {
    unsigned u = __builtin_bit_cast(unsigned, f);
    return (u16)((u + 0x7FFFu + ((u >> 16) & 1u)) >> 16);   // RNE
}
__device__ inline float bf2f(u16 h) {
    unsigned u = ((unsigned)h) << 16;
    return __builtin_bit_cast(float, u);
}

// ---------------------------------------------------------------------------
// fp32 -> (hi, lo) bf16 plane converter, float4-vectorized, grid-stride.
// ---------------------------------------------------------------------------
__global__ __launch_bounds__(256)
void split_planes(const float* __restrict__ x, u16* __restrict__ hi,
                  u16* __restrict__ lo, int n4)
{
    for (int i = blockIdx.x * blockDim.x + threadIdx.x; i < n4;
         i += gridDim.x * blockDim.x) {
        float4 v = ((const float4*)x)[i];
        ushort4 h, l;
        h.x = f2bf(v.x); l.x = f2bf(v.x - bf2f(h.x));
        h.y = f2bf(v.y); l.y = f2bf(v.y - bf2f(h.y));
        h.z = f2bf(v.z); l.z = f2bf(v.z - bf2f(h.z));
        h.w = f2bf(v.w); l.w = f2bf(v.w - bf2f(h.w));
        ((ushort4*)hi)[i] = h;
        ((ushort4*)lo)[i] = l;
    }
}

// ---------------------------------------------------------------------------
// Split-bf16 MFMA GEMM (torch Linear NT) — UNCHANGED from validated round-3.
// mode 0: fp32 Y. mode 1: (hi,lo) planes [m][N]. mode 2: transposed planes [n][MTOK].
// ---------------------------------------------------------------------------
#define GBM 128
#define GBN 64
#define GBK 32

__global__ __launch_bounds__(256)
void gemm_mfma_split(const u16* __restrict__ Ahi, const u16* __restrict__ Alo,
                     const u16* __restrict__ Bhi, const u16* __restrict__ Blo,
                     const float* __restrict__ bias, float scale, int K, int N,
                     float* __restrict__ Yf, u16* __restrict__ Yhi,
                     u16* __restrict__ Ylo, int mode)
{
    __shared__ u16 lds[2][12288];

    const int tid = threadIdx.x;
    const int lid = tid & 63;
    const int w   = tid >> 6;
    const int wm  = w >> 1, wn = w & 1;
    const int m0  = blockIdx.y * GBM;
    const int n0  = blockIdx.x * GBN;

    f32x4 acc[4][2];
    #pragma unroll
    for (int ms = 0; ms < 4; ++ms)
        #pragma unroll
        for (int ns = 0; ns < 2; ++ns)
            acc[ms][ns] = (f32x4){0.f, 0.f, 0.f, 0.f};

    auto stage = [&](int buf, int t) {
        const int k0 = t * GBK;
        #pragma unroll
        for (int j = 0; j < 6; ++j) {
            const int q = w * 6 + j;
            const u16* plane; int ldsoff, c, R0;
            if (q < 8)       { plane = Ahi; ldsoff = 0;     c = q;      R0 = m0; }
            else if (q < 16) { plane = Alo; ldsoff = 4096;  c = q - 8;  R0 = m0; }
            else if (q < 20) { plane = Bhi; ldsoff = 8192;  c = q - 16; R0 = n0; }
            else             { plane = Blo; ldsoff = 10240; c = q - 20; R0 = n0; }
            const int r  = c * 16 + (lid >> 2);
            const int ci = lid & 3;
            const int kl = ci ^ ((r >> 1) & 3);
            const u16* g = plane + (size_t)(R0 + r) * K + k0 + kl * 8;
            __builtin_amdgcn_global_load_lds(
                (const __attribute__((address_space(1))) void*)g,
                (__attribute__((address_space(3))) void*)(&lds[buf][ldsoff + c * 512]),
                16, 0, 0);
        }
    };

    auto compute = [&](int buf) {
        const u16* L = lds[buf];
        short8 ah[4], al[4], bh[2], bl[2];
        #pragma unroll
        for (int ms = 0; ms < 4; ++ms) {
            const int r   = wm * 64 + ms * 16 + (lid & 15);
            const int off = r * 32 + (((lid >> 4) ^ ((r >> 1) & 3)) * 8);
            ah[ms] = *(const short8*)&L[off];
            al[ms] = *(const short8*)&L[4096 + off];
        }
        #pragma unroll
        for (int ns = 0; ns < 2; ++ns) {
            const int r   = wn * 32 + ns * 16 + (lid & 15);
            const int off = r * 32 + (((lid >> 4) ^ ((r >> 1) & 3)) * 8);
            bh[ns] = *(const short8*)&L[8192 + off];
            bl[ns] = *(const short8*)&L[10240 + off];
        }
        #pragma unroll
        for (int ms = 0; ms < 4; ++ms)
            #pragma unroll
            for (int ns = 0; ns < 2; ++ns) {
                acc[ms][ns] = __builtin_amdgcn_mfma_f32_16x16x32_bf16(al[ms], bh[ns], acc[ms][ns], 0, 0, 0);
                acc[ms][ns] = __builtin_amdgcn_mfma_f32_16x16x32_bf16(ah[ms], bl[ns], acc[ms][ns], 0, 0, 0);
                acc[ms][ns] = __builtin_amdgcn_mfma_f32_16x16x32_bf16(ah[ms], bh[ns], acc[ms][ns], 0, 0, 0);
            }
    };

    const int nt = K / GBK;
    stage(0, 0);
    __syncthreads();
    for (int t = 0; t < nt; ++t) {
        const int buf = t & 1;
        if (t + 1 < nt) stage(buf ^ 1, t + 1);
        compute(buf);
        __syncthreads();
    }

    const int orow = (lid >> 4) * 4;
    #pragma unroll
    for (int ms = 0; ms < 4; ++ms)
        #pragma unroll
        for (int ns = 0; ns < 2; ++ns) {
            const int col = n0 + wn * 32 + ns * 16 + (lid & 15);
            const float bcol = bias[col];
            #pragma unroll
            for (int i = 0; i < 4; ++i) {
                const int row = m0 + wm * 64 + ms * 16 + orow + i;
                const float y = (acc[ms][ns][i] + bcol) * scale;
                if (mode == 0) {
                    Yf[(size_t)row * N + col] = y;
                } else if (mode == 1) {
                    const size_t idx = (size_t)row * N + col;
                    const u16 hh = f2bf(y);
                    Yhi[idx] = hh;
                    Ylo[idx] = f2bf(y - bf2f(hh));
                } else {
                    const size_t idx = (size_t)col * MTOK + row;
                    const u16 hh = f2bf(y);
                    Yhi[idx] = hh;
                    Ylo[idx] = f2bf(y - bf2f(hh));
                }
            }
        }
}

// ---------------------------------------------------------------------------
// Split-bf16 MFMA flash attention v2: swapped operands, lane-local softmax.
// Block = (b, h, 128 q rows), 4 waves x 32 q rows. KV tiles 32 rows, dbuf LDS.
// QK^T: S^T = mfma(A=K, B=Q)  -> lane holds S[q=l&15(+16mf)][k=(l>>4)*4+i(+16nf)]
// PV:   O^T = mfma(A=Vt, B=P) -> lane holds O[q=l&15(+16mf)][d=(l>>4)*4+i(+16nfd)]
// P redistributed through wave-private LDS (no barrier). LDS 48 KB -> 2 blk/CU.
// ---------------------------------------------------------------------------
__global__ __launch_bounds__(256, 2)
void attn_mfma2(const u16* __restrict__ qph, const u16* __restrict__ qpl,
                const u16* __restrict__ kph, const u16* __restrict__ kpl,
                const u16* __restrict__ vth, const u16* __restrict__ vtl,
                const float* __restrict__ qmask, const float* __restrict__ kmask,
                const float* __restrict__ pos,
                u16* __restrict__ ach, u16* __restrict__ acl)
{
    __shared__ float pp[4][1024];     // per-wave P: [32 q][32 k] f32, slot^(r&7)
    __shared__ u16  kvb[2][4][2048];  // [buf][Kh(32x64), Kl, Vth(64x32), Vtl]

    const int tid = threadIdx.x;
    const int lid = tid & 63;
    const int w   = tid >> 6;
    const int q16 = lid & 15;
    const int hi4 = lid >> 4;
    const int qt = blockIdx.x, h = blockIdx.y, b = blockIdx.z;
    const int qw = qt * 128 + w * 32;      // wave's first q row

    // ---- Q B-frags direct from global: q = qw + mf*16 + q16, k = ks*32+hi4*8+jj
    short8 qh[2][2], ql[2][2];
    #pragma unroll
    for (int mf = 0; mf < 2; ++mf)
        #pragma unroll
        for (int ks = 0; ks < 2; ++ks) {
            const size_t off = (size_t)(b * LL + qw + mf * 16 + q16) * DMODEL
                             + h * 64 + ks * 32 + hi4 * 8;
            qh[mf][ks] = *(const short8*)(qph + off);
            ql[mf][ks] = *(const short8*)(qpl + off);
        }

    // ---- staging: wave w stages plane w (Kh/Kl: 32x64 u16; Vth/Vtl: 64x32) ----
    auto stage = [&](int buf, int t) {
        const int k0 = t * KVB;
        u16* dst = &kvb[buf][w][0];
        #pragma unroll
        for (int c = 0; c < 4; ++c) {
            const u16* src;
            if (w < 2) {                       // K planes: LDS[r][sl] = K[r][sl^(r&7)]
                const int r  = c * 8 + (lid >> 3);
                const int sl = (lid & 7) ^ (r & 7);
                src = (w == 0 ? kph : kpl) +
                      (size_t)(b * LL + k0 + r) * DMODEL + h * 64 + sl * 8;
            } else {                           // Vt planes: LDS[r][sl] = Vt[r][sl^((r>>1)&3)]
                const int r  = c * 16 + (lid >> 2);
                const int sl = (lid & 3) ^ ((r >> 1) & 3);
                src = (w == 2 ? vth : vtl) +
                      (size_t)(h * 64 + r) * MTOK + b * LL + k0 + sl * 8;
            }
            __builtin_amdgcn_global_load_lds(
                (const __attribute__((address_space(1))) void*)src,
                (__attribute__((address_space(3))) void*)(dst + c * 512), 16, 0, 0);
        }
    };

    float m_run[2] = {-INFINITY, -INFINITY};
    float l_run[2] = {0.f, 0.f};
    float qml[2];
    qml[0] = qmask[b * LL + qw + q16];
    qml[1] = qmask[b * LL + qw + 16 + q16];

    f32x4 o_acc[2][4];
    #pragma unroll
    for (int mf = 0; mf < 2; ++mf)
        #pragma unroll
        for (int nfd = 0; nfd < 4; ++nfd)
            o_acc[mf][nfd] = (f32x4){0.f, 0.f, 0.f, 0.f};

    stage(0, 0);
    __syncthreads();

    for (int t = 0; t < NT; ++t) {
        const int buf = t & 1;
        const int k0  = t * KVB;

        // ---- vector pos + kmask loads (in flight under QK^T) ----
        float4 kmv[2], posr[2][2];
        #pragma unroll
        for (int nf = 0; nf < 2; ++nf)
            kmv[nf] = *(const float4*)(kmask + b * LL + k0 + nf * 16 + hi4 * 4);
        #pragma unroll
        for (int mf = 0; mf < 2; ++mf)
            #pragma unroll
            for (int nf = 0; nf < 2; ++nf)
                posr[mf][nf] = *(const float4*)(pos +
                    ((size_t)(b * LL + qw + mf * 16 + q16)) * LL +
                    k0 + nf * 16 + hi4 * 4);

        if (t + 1 < NT) stage(buf ^ 1, t + 1);

        // ---- S^T = K · Q^T (3-term split) ----
        f32x4 s_acc[2][2];
        #pragma unroll
        for (int mf = 0; mf < 2; ++mf)
            #pragma unroll
            for (int nf = 0; nf < 2; ++nf)
                s_acc[mf][nf] = (f32x4){0.f, 0.f, 0.f, 0.f};

        #pragma unroll
        for (int ks = 0; ks < 2; ++ks)
            #pragma unroll
            for (int nf = 0; nf < 2; ++nf) {
                const int r  = nf * 16 + q16;
                const int sl = (ks * 4 + hi4) ^ (r & 7);
                short8 kbh = *(const short8*)(&kvb[buf][0][r * 64 + sl * 8]);
                short8 kbl = *(const short8*)(&kvb[buf][1][r * 64 + sl * 8]);
                #pragma unroll
                for (int mf = 0; mf < 2; ++mf) {
                    s_acc[mf][nf] = __builtin_amdgcn_mfma_f32_16x16x32_bf16(kbl, qh[mf][ks], s_acc[mf][nf], 0, 0, 0);
                    s_acc[mf][nf] = __builtin_amdgcn_mfma_f32_16x16x32_bf16(kbh, ql[mf][ks], s_acc[mf][nf], 0, 0, 0);
                    s_acc[mf][nf] = __builtin_amdgcn_mfma_f32_16x16x32_bf16(kbh, qh[mf][ks], s_acc[mf][nf], 0, 0, 0);
                }
            }

        // ---- mask + pos + online softmax (lane-local rows) + P -> wave LDS ----
        #pragma unroll
        for (int mf = 0; mf < 2; ++mf) {
            float v[2][4];
            #pragma unroll
            for (int nf = 0; nf < 2; ++nf) {
                const float* km = (const float*)&kmv[nf];
                const float* pr = (const float*)&posr[mf][nf];
                #pragma unroll
                for (int i = 0; i < 4; ++i)
                    v[nf][i] = (qml[mf] * km[i] == 0.f)
                               ? -INFINITY : s_acc[mf][nf][i] + pr[i];
            }
            float rm = fmaxf(fmaxf(fmaxf(v[0][0], v[0][1]), fmaxf(v[0][2], v[0][3])),
                             fmaxf(fmaxf(v[1][0], v[1][1]), fmaxf(v[1][2], v[1][3])));
            rm = fmaxf(rm, __shfl_xor(rm, 16));
            rm = fmaxf(rm, __shfl_xor(rm, 32));
            const float mn = fmaxf(m_run[mf], rm);
            const float c  = __expf(m_run[mf] - mn);
            float ls = 0.f;
            float p[2][4];
            #pragma unroll
            for (int nf = 0; nf < 2; ++nf)
                #pragma unroll
                for (int i = 0; i < 4; ++i) {
                    p[nf][i] = __expf(v[nf][i] - mn);
                    ls += p[nf][i];
                }
            ls += __shfl_xor(ls, 16);
            ls += __shfl_xor(ls, 32);
            l_run[mf] = l_run[mf] * c + ls;
            m_run[mf] = mn;
            #pragma unroll
            for (int nfd = 0; nfd < 4; ++nfd)
                o_acc[mf][nfd] *= c;
            const int r = mf * 16 + q16;
            #pragma unroll
            for (int nf = 0; nf < 2; ++nf) {
                const int sl = (nf * 4 + hi4) ^ (r & 7);
                *(f32x4*)&pp[w][r * 32 + sl * 4] =
                    (f32x4){p[nf][0], p[nf][1], p[nf][2], p[nf][3]};
            }
        }

        // ---- P B-frags from wave LDS (trunc split), PV = Vt · P^T ----
        short8 pah[2], pal[2];
        #pragma unroll
        for (int mf = 0; mf < 2; ++mf) {
            const int r  = mf * 16 + q16;
            const int s0 = (hi4 * 2)     ^ (r & 7);
            const int s1 = (hi4 * 2 + 1) ^ (r & 7);
            f32x4 pa = *(const f32x4*)&pp[w][r * 32 + s0 * 4];
            f32x4 pb = *(const f32x4*)&pp[w][r * 32 + s1 * 4];
            float f[8] = {pa[0], pa[1], pa[2], pa[3], pb[0], pb[1], pb[2], pb[3]};
            short8 hv, lv;
            #pragma unroll
            for (int jj = 0; jj < 8; ++jj) {
                const unsigned u = __builtin_bit_cast(unsigned, f[jj]);
                hv[jj] = (short)(u >> 16);
                const float lof = f[jj] - __builtin_bit_cast(float, u & 0xFFFF0000u);
                lv[jj] = (short)(__builtin_bit_cast(unsigned, lof) >> 16);
            }
            pah[mf] = hv; pal[mf] = lv;
        }
        #pragma unroll
        for (int nfd = 0; nfd < 4; ++nfd) {
            const int r  = nfd * 16 + q16;
            const int sl = hi4 ^ ((r >> 1) & 3);
            short8 vbh = *(const short8*)(&kvb[buf][2][r * 32 + sl * 8]);
            short8 vbl = *(const short8*)(&kvb[buf][3][r * 32 + sl * 8]);
            #pragma unroll
            for (int mf = 0; mf < 2; ++mf) {
                o_acc[mf][nfd] = __builtin_amdgcn_mfma_f32_16x16x32_bf16(vbl, pah[mf], o_acc[mf][nfd], 0, 0, 0);
                o_acc[mf][nfd] = __builtin_amdgcn_mfma_f32_16x16x32_bf16(vbh, pal[mf], o_acc[mf][nfd], 0, 0, 0);
                o_acc[mf][nfd] = __builtin_amdgcn_mfma_f32_16x16x32_bf16(vbh, pah[mf], o_acc[mf][nfd], 0, 0, 0);
            }
        }

        __syncthreads();   // drain prefetch; all waves done with kvb[buf]
    }

    // ---- normalize + write combined-head (hi,lo) planes [B*L][DMODEL] ----
    #pragma unroll
    for (int mf = 0; mf < 2; ++mf) {
        const float inv = 1.0f / l_run[mf];
        const size_t rb = (size_t)(b * LL + qw + mf * 16 + q16) * DMODEL + h * 64;
        #pragma unroll
        for (int nfd = 0; nfd < 4; ++nfd) {
            ushort4 hv, lv;
            #pragma unroll
            for (int i = 0; i < 4; ++i) {
                const float y  = o_acc[mf][nfd][i] * inv;
                const u16 hh   = f2bf(y);
                (&hv.x)[i] = hh;
                (&lv.x)[i] = f2bf(y - bf2f(hh));
            }
            *(ushort4*)(ach + rb + nfd * 16 + hi4 * 4) = hv;
            *(ushort4*)(acl + rb + nfd * 16 + hi4 * 4) = lv;
        }
    }
}

// ---------------------------------------------------------------------------
extern "C" void kernel_launch(void* const* d_in, const int* in_sizes, int n_in,
                              void* d_out, int out_size, void* d_ws, size_t ws_size,
                              hipStream_t stream)
{
    const float* q     = (const float*)d_in[0];
    const float* k     = (const float*)d_in[1];
    const float* qmask = (const float*)d_in[2];
    const float* kmask = (const float*)d_in[3];
    const float* pos   = (const float*)d_in[4];
    const float* Wq    = (const float*)d_in[5];
    const float* bq    = (const float*)d_in[6];
    const float* Wk    = (const float*)d_in[7];
    const float* bk    = (const float*)d_in[8];
    const float* Wv    = (const float*)d_in[9];
    const float* bv    = (const float*)d_in[10];
    const float* Wo    = (const float*)d_in[11];
    const float* bo    = (const float*)d_in[12];
    float* out = (float*)d_out;

    const size_t P  = (size_t)MTOK * DMODEL;   // 4M elems / plane
    const size_t PW = (size_t)DMODEL * DMODEL;

    u16* base = (u16*)d_ws;
    u16* qp_h = base;            u16* qp_l = qp_h + P;
    u16* kp_h = base + 2 * P;    u16* kp_l = kp_h + P;
    u16* bufA = base + 4 * P;    // q-input planes, later V^T planes (2P)
    u16* bufB = base + 6 * P;    // k-input planes, later attn-out planes (2P)
    u16* wq_h = base + 8 * P;    u16* wq_l = wq_h + PW;
    u16* wk_h = wq_l + PW;       u16* wk_l = wk_h + PW;
    u16* wv_h = wk_l + PW;       u16* wv_l = wv_h + PW;
    u16* wo_h = wv_l + PW;       u16* wo_l = wo_h + PW;
    // total: 8P + 8PW u16 = 80 MB

    split_planes<<<1024, 256, 0, stream>>>(q,  bufA, bufA + P, (int)(P / 4));
    split_planes<<<1024, 256, 0, stream>>>(k,  bufB, bufB + P, (int)(P / 4));
    split_planes<<<512,  256, 0, stream>>>(Wq, wq_h, wq_l, (int)(PW / 4));
    split_planes<<<512,  256, 0, stream>>>(Wk, wk_h, wk_l, (int)(PW / 4));
    split_planes<<<512,  256, 0, stream>>>(Wv, wv_h, wv_l, (int)(PW / 4));
    split_planes<<<512,  256, 0, stream>>>(Wo, wo_h, wo_l, (int)(PW / 4));

    const dim3 gb(DMODEL / GBN, MTOK / GBM);   // (16, 32) = 512 blocks
    const dim3 ga(LL / 128, NHEAD, BB);        // (16, 16, 2) = 512 blocks

    // qp = (q @ Wq^T + bq) * dkh^-0.5   -> planes [m][N]
    gemm_mfma_split<<<gb, 256, 0, stream>>>(bufA, bufA + P, wq_h, wq_l, bq, 0.125f,
                                            DMODEL, DMODEL, nullptr, qp_h, qp_l, 1);
    // kp = k @ Wk^T + bk                -> planes [m][N]
    gemm_mfma_split<<<gb, 256, 0, stream>>>(bufB, bufB + P, wk_h, wk_l, bk, 1.0f,
                                            DMODEL, DMODEL, nullptr, kp_h, kp_l, 1);
    // vpT = (kp @ Wv^T + bv)^T          -> transposed planes [n][MTOK] (into bufA)
    gemm_mfma_split<<<gb, 256, 0, stream>>>(kp_h, kp_l, wv_h, wv_l, bv, 1.0f,
                                            DMODEL, DMODEL, nullptr, bufA, bufA + P, 2);
    // flash attention v2 (swapped-operand split-bf16 MFMA) -> planes (into bufB)
    attn_mfma2<<<ga, 256, 0, stream>>>(qp_h, qp_l, kp_h, kp_l, bufA, bufA + P,
                                       qmask, kmask, pos, bufB, bufB + P);
    // out = ac @ Wo^T + bo              -> fp32 d_out
    gemm_mfma_split<<<gb, 256, 0, stream>>>(bufB, bufB + P, wo_h, wo_l, bo, 1.0f,
                                            DMODEL, DMODEL, out, nullptr, nullptr, 0);
}

// Round 5
// 470.073 us; speedup vs baseline: 1.3178x; 1.0162x over previous
//
#include <hip/hip_runtime.h>
#include <math.h>

#define BB 2
#define LL 2048
#define DMODEL 1024
#define NHEAD 16
#define MTOK 4096            // BB*LL
#define KVB 32               // attention KV tile rows
#define NT (LL / KVB)        // 64 KV tiles

typedef unsigned short u16;
typedef __attribute__((ext_vector_type(8))) short short8;
typedef __attribute__((ext_vector_type(4))) float f32x4;

// ---------------------------------------------------------------------------
// bf16 split helpers: x ≈ bf2f(hi) + bf2f(lo), residual ~2^-17 x
// ---------------------------------------------------------------------------
__device__ __host__ inline u16 f2bf(float f) {
    unsigned u = __builtin_bit_cast(unsigned, f);
    return (u16)((u + 0x7FFFu + ((u >> 16) & 1u)) >> 16);   // RNE
}
__device__ inline float bf2f(u16 h) {
    unsigned u = ((unsigned)h) << 16;
    return __builtin_bit_cast(float, u);
}

// ---------------------------------------------------------------------------
// fp32 -> (hi,lo) bf16 plane converters, float4-vectorized, multi-tensor.
// ---------------------------------------------------------------------------
__device__ inline void split_one(const float* __restrict__ x, u16* __restrict__ hi,
                                 u16* __restrict__ lo, int n4)
{
    for (int i = blockIdx.x * blockDim.x + threadIdx.x; i < n4;
         i += gridDim.x * blockDim.x) {
        float4 v = ((const float4*)x)[i];
        ushort4 h, l;
        h.x = f2bf(v.x); l.x = f2bf(v.x - bf2f(h.x));
        h.y = f2bf(v.y); l.y = f2bf(v.y - bf2f(h.y));
        h.z = f2bf(v.z); l.z = f2bf(v.z - bf2f(h.z));
        h.w = f2bf(v.w); l.w = f2bf(v.w - bf2f(h.w));
        ((ushort4*)hi)[i] = h;
        ((ushort4*)lo)[i] = l;
    }
}

__global__ __launch_bounds__(256)
void split_planes2(const float* __restrict__ x0, u16* __restrict__ h0, u16* __restrict__ l0,
                   const float* __restrict__ x1, u16* __restrict__ h1, u16* __restrict__ l1,
                   int n4)
{
    if (blockIdx.y == 0) split_one(x0, h0, l0, n4);
    else                 split_one(x1, h1, l1, n4);
}

__global__ __launch_bounds__(256)
void split_planes4(const float* __restrict__ x0, u16* __restrict__ h0, u16* __restrict__ l0,
                   const float* __restrict__ x1, u16* __restrict__ h1, u16* __restrict__ l1,
                   const float* __restrict__ x2, u16* __restrict__ h2, u16* __restrict__ l2,
                   const float* __restrict__ x3, u16* __restrict__ h3, u16* __restrict__ l3,
                   int n4)
{
    switch (blockIdx.y & 3) {
        case 0: split_one(x0, h0, l0, n4); break;
        case 1: split_one(x1, h1, l1, n4); break;
        case 2: split_one(x2, h2, l2, n4); break;
        default: split_one(x3, h3, l3, n4); break;
    }
}

// ---------------------------------------------------------------------------
// Split-bf16 MFMA GEMM (torch Linear NT). Main loop unchanged (HW-validated).
// mode 0: fp32 Y [m][N]. mode 1: (hi,lo) planes [m][N].
// mode 2: transposed planes [n][MTOK] with PACKED 8B stores (4 consecutive
//         MTOK-elements per lane -> uint2), fixing the 2B/lane scatter.
// ---------------------------------------------------------------------------
#define GBM 128
#define GBN 64
#define GBK 32

__global__ __launch_bounds__(256)
void gemm_mfma_split(const u16* __restrict__ Ahi, const u16* __restrict__ Alo,
                     const u16* __restrict__ Bhi, const u16* __restrict__ Blo,
                     const float* __restrict__ bias, float scale, int K, int N,
                     float* __restrict__ Yf, u16* __restrict__ Yhi,
                     u16* __restrict__ Ylo, int mode)
{
    __shared__ u16 lds[2][12288];

    const int tid = threadIdx.x;
    const int lid = tid & 63;
    const int w   = tid >> 6;
    const int wm  = w >> 1, wn = w & 1;
    const int m0  = blockIdx.y * GBM;
    const int n0  = blockIdx.x * GBN;

    f32x4 acc[4][2];
    #pragma unroll
    for (int ms = 0; ms < 4; ++ms)
        #pragma unroll
        for (int ns = 0; ns < 2; ++ns)
            acc[ms][ns] = (f32x4){0.f, 0.f, 0.f, 0.f};

    auto stage = [&](int buf, int t) {
        const int k0 = t * GBK;
        #pragma unroll
        for (int j = 0; j < 6; ++j) {
            const int q = w * 6 + j;
            const u16* plane; int ldsoff, c, R0;
            if (q < 8)       { plane = Ahi; ldsoff = 0;     c = q;      R0 = m0; }
            else if (q < 16) { plane = Alo; ldsoff = 4096;  c = q - 8;  R0 = m0; }
            else if (q < 20) { plane = Bhi; ldsoff = 8192;  c = q - 16; R0 = n0; }
            else             { plane = Blo; ldsoff = 10240; c = q - 20; R0 = n0; }
            const int r  = c * 16 + (lid >> 2);
            const int ci = lid & 3;
            const int kl = ci ^ ((r >> 1) & 3);
            const u16* g = plane + (size_t)(R0 + r) * K + k0 + kl * 8;
            __builtin_amdgcn_global_load_lds(
                (const __attribute__((address_space(1))) void*)g,
                (__attribute__((address_space(3))) void*)(&lds[buf][ldsoff + c * 512]),
                16, 0, 0);
        }
    };

    auto compute = [&](int buf) {
        const u16* L = lds[buf];
        short8 ah[4], al[4], bh[2], bl[2];
        #pragma unroll
        for (int ms = 0; ms < 4; ++ms) {
            const int r   = wm * 64 + ms * 16 + (lid & 15);
            const int off = r * 32 + (((lid >> 4) ^ ((r >> 1) & 3)) * 8);
            ah[ms] = *(const short8*)&L[off];
            al[ms] = *(const short8*)&L[4096 + off];
        }
        #pragma unroll
        for (int ns = 0; ns < 2; ++ns) {
            const int r   = wn * 32 + ns * 16 + (lid & 15);
            const int off = r * 32 + (((lid >> 4) ^ ((r >> 1) & 3)) * 8);
            bh[ns] = *(const short8*)&L[8192 + off];
            bl[ns] = *(const short8*)&L[10240 + off];
        }
        #pragma unroll
        for (int ms = 0; ms < 4; ++ms)
            #pragma unroll
            for (int ns = 0; ns < 2; ++ns) {
                acc[ms][ns] = __builtin_amdgcn_mfma_f32_16x16x32_bf16(al[ms], bh[ns], acc[ms][ns], 0, 0, 0);
                acc[ms][ns] = __builtin_amdgcn_mfma_f32_16x16x32_bf16(ah[ms], bl[ns], acc[ms][ns], 0, 0, 0);
                acc[ms][ns] = __builtin_amdgcn_mfma_f32_16x16x32_bf16(ah[ms], bh[ns], acc[ms][ns], 0, 0, 0);
            }
    };

    const int nt = K / GBK;
    stage(0, 0);
    __syncthreads();
    for (int t = 0; t < nt; ++t) {
        const int buf = t & 1;
        if (t + 1 < nt) stage(buf ^ 1, t + 1);
        compute(buf);
        __syncthreads();
    }

    const int orow = (lid >> 4) * 4;
    #pragma unroll
    for (int ms = 0; ms < 4; ++ms)
        #pragma unroll
        for (int ns = 0; ns < 2; ++ns) {
            const int col = n0 + wn * 32 + ns * 16 + (lid & 15);
            const float bcol = bias[col];
            if (mode == 2) {
                // packed Vt store: 4 consecutive MTOK elements per lane
                const int r0 = m0 + wm * 64 + ms * 16 + orow;
                unsigned ph[2] = {0, 0}, pl[2] = {0, 0};
                #pragma unroll
                for (int i = 0; i < 4; ++i) {
                    const float y = (acc[ms][ns][i] + bcol) * scale;
                    const u16 hh = f2bf(y);
                    const u16 ll = f2bf(y - bf2f(hh));
                    ph[i >> 1] |= ((unsigned)hh) << ((i & 1) * 16);
                    pl[i >> 1] |= ((unsigned)ll) << ((i & 1) * 16);
                }
                const size_t idx = (size_t)col * MTOK + r0;
                *(uint2*)(Yhi + idx) = make_uint2(ph[0], ph[1]);
                *(uint2*)(Ylo + idx) = make_uint2(pl[0], pl[1]);
            } else {
                #pragma unroll
                for (int i = 0; i < 4; ++i) {
                    const int row = m0 + wm * 64 + ms * 16 + orow + i;
                    const float y = (acc[ms][ns][i] + bcol) * scale;
                    if (mode == 0) {
                        Yf[(size_t)row * N + col] = y;
                    } else {
                        const size_t idx = (size_t)row * N + col;
                        const u16 hh = f2bf(y);
                        Yhi[idx] = hh;
                        Ylo[idx] = f2bf(y - bf2f(hh));
                    }
                }
            }
        }
}

// ---------------------------------------------------------------------------
// Split-bf16 MFMA flash attention v3: same math as v2 (bit-identical output),
// but block = (b, h, 64 q rows), 4 waves x 16 q rows -> grid 1024, LDS 40 KB
// -> 4 blocks/CU (occupancy 2x). KV tiles 32 rows double-buffered (shared by
// all 4 waves); per-wave P LDS 2 KB.
// ---------------------------------------------------------------------------
__global__ __launch_bounds__(256, 4)
void attn_mfma3(const u16* __restrict__ qph, const u16* __restrict__ qpl,
                const u16* __restrict__ kph, const u16* __restrict__ kpl,
                const u16* __restrict__ vth, const u16* __restrict__ vtl,
                const float* __restrict__ qmask, const float* __restrict__ kmask,
                const float* __restrict__ pos,
                u16* __restrict__ ach, u16* __restrict__ acl)
{
    __shared__ float pp[4][512];      // per-wave P: [16 q][32 k] f32, slot^(r&7)
    __shared__ u16  kvb[2][4][2048];  // [buf][Kh(32x64), Kl, Vth(64x32), Vtl]

    const int tid = threadIdx.x;
    const int lid = tid & 63;
    const int w   = tid >> 6;
    const int q16 = lid & 15;
    const int hi4 = lid >> 4;
    const int qt = blockIdx.x, h = blockIdx.y, b = blockIdx.z;
    const int qw = qt * 64 + w * 16;       // wave's first q row

    // ---- Q B-frags direct from global: q = qw + q16, k = ks*32 + hi4*8 + jj
    short8 qh[2], ql[2];
    #pragma unroll
    for (int ks = 0; ks < 2; ++ks) {
        const size_t off = (size_t)(b * LL + qw + q16) * DMODEL
                         + h * 64 + ks * 32 + hi4 * 8;
        qh[ks] = *(const short8*)(qph + off);
        ql[ks] = *(const short8*)(qpl + off);
    }

    // ---- staging: wave w stages plane w (Kh/Kl: 32x64 u16; Vth/Vtl: 64x32) ----
    auto stage = [&](int buf, int t) {
        const int k0 = t * KVB;
        u16* dst = &kvb[buf][w][0];
        #pragma unroll
        for (int c = 0; c < 4; ++c) {
            const u16* src;
            if (w < 2) {                       // K planes: LDS[r][sl] = K[r][sl^(r&7)]
                const int r  = c * 8 + (lid >> 3);
                const int sl = (lid & 7) ^ (r & 7);
                src = (w == 0 ? kph : kpl) +
                      (size_t)(b * LL + k0 + r) * DMODEL + h * 64 + sl * 8;
            } else {                           // Vt planes: LDS[r][sl] = Vt[r][sl^((r>>1)&3)]
                const int r  = c * 16 + (lid >> 2);
                const int sl = (lid & 3) ^ ((r >> 1) & 3);
                src = (w == 2 ? vth : vtl) +
                      (size_t)(h * 64 + r) * MTOK + b * LL + k0 + sl * 8;
            }
            __builtin_amdgcn_global_load_lds(
                (const __attribute__((address_space(1))) void*)src,
                (__attribute__((address_space(3))) void*)(dst + c * 512), 16, 0, 0);
        }
    };

    float m_run = -INFINITY, l_run = 0.f;
    const float qml = qmask[b * LL + qw + q16];

    f32x4 o_acc[4];
    #pragma unroll
    for (int nfd = 0; nfd < 4; ++nfd)
        o_acc[nfd] = (f32x4){0.f, 0.f, 0.f, 0.f};

    stage(0, 0);
    __syncthreads();

    for (int t = 0; t < NT; ++t) {
        const int buf = t & 1;
        const int k0  = t * KVB;

        // ---- vector pos + kmask loads (in flight under QK^T) ----
        float4 kmv[2], posr[2];
        #pragma unroll
        for (int nf = 0; nf < 2; ++nf) {
            kmv[nf]  = *(const float4*)(kmask + b * LL + k0 + nf * 16 + hi4 * 4);
            posr[nf] = *(const float4*)(pos +
                ((size_t)(b * LL + qw + q16)) * LL + k0 + nf * 16 + hi4 * 4);
        }

        if (t + 1 < NT) stage(buf ^ 1, t + 1);

        // ---- S^T = K · Q^T (3-term split) ----
        f32x4 s_acc[2];
        s_acc[0] = (f32x4){0.f, 0.f, 0.f, 0.f};
        s_acc[1] = (f32x4){0.f, 0.f, 0.f, 0.f};

        #pragma unroll
        for (int ks = 0; ks < 2; ++ks)
            #pragma unroll
            for (int nf = 0; nf < 2; ++nf) {
                const int r  = nf * 16 + q16;
                const int sl = (ks * 4 + hi4) ^ (r & 7);
                short8 kbh = *(const short8*)(&kvb[buf][0][r * 64 + sl * 8]);
                short8 kbl = *(const short8*)(&kvb[buf][1][r * 64 + sl * 8]);
                s_acc[nf] = __builtin_amdgcn_mfma_f32_16x16x32_bf16(kbl, qh[ks], s_acc[nf], 0, 0, 0);
                s_acc[nf] = __builtin_amdgcn_mfma_f32_16x16x32_bf16(kbh, ql[ks], s_acc[nf], 0, 0, 0);
                s_acc[nf] = __builtin_amdgcn_mfma_f32_16x16x32_bf16(kbh, qh[ks], s_acc[nf], 0, 0, 0);
            }

        // ---- mask + pos + online softmax (lane-local row q16) ----
        {
            float v[2][4];
            #pragma unroll
            for (int nf = 0; nf < 2; ++nf) {
                const float* km = (const float*)&kmv[nf];
                const float* pr = (const float*)&posr[nf];
                #pragma unroll
                for (int i = 0; i < 4; ++i)
                    v[nf][i] = (qml * km[i] == 0.f)
                               ? -INFINITY : s_acc[nf][i] + pr[i];
            }
            float rm = fmaxf(fmaxf(fmaxf(v[0][0], v[0][1]), fmaxf(v[0][2], v[0][3])),
                             fmaxf(fmaxf(v[1][0], v[1][1]), fmaxf(v[1][2], v[1][3])));
            rm = fmaxf(rm, __shfl_xor(rm, 16));
            rm = fmaxf(rm, __shfl_xor(rm, 32));
            const float mn = fmaxf(m_run, rm);
            const float c  = __expf(m_run - mn);
            float ls = 0.f;
            float p[2][4];
            #pragma unroll
            for (int nf = 0; nf < 2; ++nf)
                #pragma unroll
                for (int i = 0; i < 4; ++i) {
                    p[nf][i] = __expf(v[nf][i] - mn);
                    ls += p[nf][i];
                }
            ls += __shfl_xor(ls, 16);
            ls += __shfl_xor(ls, 32);
            l_run = l_run * c + ls;
            m_run = mn;
            #pragma unroll
            for (int nfd = 0; nfd < 4; ++nfd)
                o_acc[nfd] *= c;
            const int r = q16;
            #pragma unroll
            for (int nf = 0; nf < 2; ++nf) {
                const int sl = (nf * 4 + hi4) ^ (r & 7);
                *(f32x4*)&pp[w][r * 32 + sl * 4] =
                    (f32x4){p[nf][0], p[nf][1], p[nf][2], p[nf][3]};
            }
        }

        // ---- P B-frags from wave LDS (trunc split), PV = Vt · P^T ----
        short8 pah, pal;
        {
            const int r  = q16;
            const int s0 = (hi4 * 2)     ^ (r & 7);
            const int s1 = (hi4 * 2 + 1) ^ (r & 7);
            f32x4 pa = *(const f32x4*)&pp[w][r * 32 + s0 * 4];
            f32x4 pb = *(const f32x4*)&pp[w][r * 32 + s1 * 4];
            float f[8] = {pa[0], pa[1], pa[2], pa[3], pb[0], pb[1], pb[2], pb[3]};
            #pragma unroll
            for (int jj = 0; jj < 8; ++jj) {
                const unsigned u = __builtin_bit_cast(unsigned, f[jj]);
                pah[jj] = (short)(u >> 16);
                const float lof = f[jj] - __builtin_bit_cast(float, u & 0xFFFF0000u);
                pal[jj] = (short)(__builtin_bit_cast(unsigned, lof) >> 16);
            }
        }
        #pragma unroll
        for (int nfd = 0; nfd < 4; ++nfd) {
            const int r  = nfd * 16 + q16;
            const int sl = hi4 ^ ((r >> 1) & 3);
            short8 vbh = *(const short8*)(&kvb[buf][2][r * 32 + sl * 8]);
            short8 vbl = *(const short8*)(&kvb[buf][3][r * 32 + sl * 8]);
            o_acc[nfd] = __builtin_amdgcn_mfma_f32_16x16x32_bf16(vbl, pah, o_acc[nfd], 0, 0, 0);
            o_acc[nfd] = __builtin_amdgcn_mfma_f32_16x16x32_bf16(vbh, pal, o_acc[nfd], 0, 0, 0);
            o_acc[nfd] = __builtin_amdgcn_mfma_f32_16x16x32_bf16(vbh, pah, o_acc[nfd], 0, 0, 0);
        }

        __syncthreads();   // drain prefetch; all waves done with kvb[buf]
    }

    // ---- normalize + write combined-head (hi,lo) planes [B*L][DMODEL] ----
    {
        const float inv = 1.0f / l_run;
        const size_t rb = (size_t)(b * LL + qw + q16) * DMODEL + h * 64;
        #pragma unroll
        for (int nfd = 0; nfd < 4; ++nfd) {
            ushort4 hv, lv;
            #pragma unroll
            for (int i = 0; i < 4; ++i) {
                const float y  = o_acc[nfd][i] * inv;
                const u16 hh   = f2bf(y);
                (&hv.x)[i] = hh;
                (&lv.x)[i] = f2bf(y - bf2f(hh));
            }
            *(ushort4*)(ach + rb + nfd * 16 + hi4 * 4) = hv;
            *(ushort4*)(acl + rb + nfd * 16 + hi4 * 4) = lv;
        }
    }
}

// ---------------------------------------------------------------------------
extern "C" void kernel_launch(void* const* d_in, const int* in_sizes, int n_in,
                              void* d_out, int out_size, void* d_ws, size_t ws_size,
                              hipStream_t stream)
{
    const float* q     = (const float*)d_in[0];
    const float* k     = (const float*)d_in[1];
    const float* qmask = (const float*)d_in[2];
    const float* kmask = (const float*)d_in[3];
    const float* pos   = (const float*)d_in[4];
    const float* Wq    = (const float*)d_in[5];
    const float* bq    = (const float*)d_in[6];
    const float* Wk    = (const float*)d_in[7];
    const float* bk    = (const float*)d_in[8];
    const float* Wv    = (const float*)d_in[9];
    const float* bv    = (const float*)d_in[10];
    const float* Wo    = (const float*)d_in[11];
    const float* bo    = (const float*)d_in[12];
    float* out = (float*)d_out;

    const size_t P  = (size_t)MTOK * DMODEL;   // 4M elems / plane
    const size_t PW = (size_t)DMODEL * DMODEL;

    u16* base = (u16*)d_ws;
    u16* qp_h = base;            u16* qp_l = qp_h + P;
    u16* kp_h = base + 2 * P;    u16* kp_l = kp_h + P;
    u16* bufA = base + 4 * P;    // q-input planes, later V^T planes (2P)
    u16* bufB = base + 6 * P;    // k-input planes, later attn-out planes (2P)
    u16* wq_h = base + 8 * P;    u16* wq_l = wq_h + PW;
    u16* wk_h = wq_l + PW;       u16* wk_l = wk_h + PW;
    u16* wv_h = wk_l + PW;       u16* wv_l = wv_h + PW;
    u16* wo_h = wv_l + PW;       u16* wo_l = wo_h + PW;
    // total: 8P + 8PW u16 = 80 MB

    // ---- split inputs & weights into bf16 (hi,lo) planes (2 fused launches) ----
    split_planes2<<<dim3(1024, 2), 256, 0, stream>>>(
        q, bufA, bufA + P, k, bufB, bufB + P, (int)(P / 4));
    split_planes4<<<dim3(512, 4), 256, 0, stream>>>(
        Wq, wq_h, wq_l, Wk, wk_h, wk_l, Wv, wv_h, wv_l, Wo, wo_h, wo_l,
        (int)(PW / 4));

    const dim3 gb(DMODEL / GBN, MTOK / GBM);   // (16, 32) = 512 blocks
    const dim3 ga(LL / 64, NHEAD, BB);         // (32, 16, 2) = 1024 blocks

    // qp = (q @ Wq^T + bq) * dkh^-0.5   -> planes [m][N]
    gemm_mfma_split<<<gb, 256, 0, stream>>>(bufA, bufA + P, wq_h, wq_l, bq, 0.125f,
                                            DMODEL, DMODEL, nullptr, qp_h, qp_l, 1);
    // kp = k @ Wk^T + bk                -> planes [m][N]
    gemm_mfma_split<<<gb, 256, 0, stream>>>(bufB, bufB + P, wk_h, wk_l, bk, 1.0f,
                                            DMODEL, DMODEL, nullptr, kp_h, kp_l, 1);
    // vpT = (kp @ Wv^T + bv)^T          -> transposed planes [n][MTOK] (into bufA)
    gemm_mfma_split<<<gb, 256, 0, stream>>>(kp_h, kp_l, wv_h, wv_l, bv, 1.0f,
                                            DMODEL, DMODEL, nullptr, bufA, bufA + P, 2);
    // flash attention v3 (4 blk/CU) -> combined-head planes (into bufB)
    attn_mfma3<<<ga, 256, 0, stream>>>(qp_h, qp_l, kp_h, kp_l, bufA, bufA + P,
                                       qmask, kmask, pos, bufB, bufB + P);
    // out = ac @ Wo^T + bo              -> fp32 d_out
    gemm_mfma_split<<<gb, 256, 0, stream>>>(bufB, bufB + P, wo_h, wo_l, bo, 1.0f,
                                            DMODEL, DMODEL, out, nullptr, nullptr, 0);
}